// Round 1
// baseline (338.170 us; speedup 1.0000x reference)
//
#include <hip/hip_runtime.h>

// Bilinear resampling: feature_map [C,H,W] fp32, target_uv [N,2] fp32, downscale (int scalar)
// out [C,N] fp32.
constexpr int C = 128, H = 376, W = 1248;
constexpr int HW = H * W;
constexpr int CPG = 2;          // channels per group (per-XCD L2 working set = CPG*1.88MB)
constexpr int CG  = C / CPG;    // grid.y

__global__ __launch_bounds__(256) void BilinearResampling_kernel(
    const float* __restrict__ fmap,
    const float* __restrict__ uv,
    const int*   __restrict__ dsp,
    float*       __restrict__ out,
    int N)
{
    int n = blockIdx.x * 256 + threadIdx.x;
    if (n >= N) return;

    float dsf = (float)dsp[0];
    float2 p = ((const float2*)uv)[n];     // 8B aligned, coalesced
    float u = p.x / dsf;
    float v = p.y / dsf;

    int u_lo = (int)u;                      // trunc == floor (u,v >= 0)
    int v_lo = (int)v;
    float du = u - (float)u_lo;
    float dv = v - (float)v_lo;

    float w00 = (1.0f - dv) * (1.0f - du);
    float w10 = dv * (1.0f - du);
    float w01 = (1.0f - dv) * du;
    float w11 = dv * du;

    int cbase = blockIdx.y * CPG;
    const float* fp = fmap + (size_t)cbase * HW + (size_t)v_lo * W + u_lo;
    float*       op = out  + (size_t)cbase * N + n;

#pragma unroll
    for (int c = 0; c < CPG; ++c) {
        float f00 = fp[0];
        float f01 = fp[1];
        float f10 = fp[W];
        float f11 = fp[W + 1];
        float r = f00 * w00 + f10 * w10 + f01 * w01 + f11 * w11;
        __builtin_nontemporal_store(r, op);   // streaming output: don't pollute L2/L3
        fp += HW;
        op += N;
    }
}

extern "C" void kernel_launch(void* const* d_in, const int* in_sizes, int n_in,
                              void* d_out, int out_size, void* d_ws, size_t ws_size,
                              hipStream_t stream)
{
    const float* fmap = (const float*)d_in[0];
    const float* uv   = (const float*)d_in[1];
    const int*   dsp  = (const int*)d_in[2];
    float*       out  = (float*)d_out;

    int N = in_sizes[1] / 2;   // target_uv has N*2 elements

    dim3 grid((N + 255) / 256, CG);
    dim3 block(256);
    BilinearResampling_kernel<<<grid, block, 0, stream>>>(fmap, uv, dsp, out, N);
}

// Round 2
// 232.858 us; speedup vs baseline: 1.4523x; 1.4523x over previous
//
#include <hip/hip_runtime.h>

// Bilinear resampling: feature_map [C,H,W] fp32, target_uv [N,2] fp32, downscale (int scalar)
// out [C,N] fp32.
constexpr int C = 128, H = 376, W = 1248;
constexpr int HW = H * W;
constexpr int CPG = 2;          // channels per group (per-XCD L2 working set = CPG*1.88MB < 4MB)
constexpr int CG  = C / CPG;    // 64 channel groups
constexpr int NXCD = 8;
constexpr int GPX  = CG / NXCD; // 8 channel groups owned per XCD

__global__ __launch_bounds__(256) void BilinearResampling_kernel(
    const float* __restrict__ fmap,
    const float* __restrict__ uv,
    const int*   __restrict__ dsp,
    float*       __restrict__ out,
    int N, int NBX)
{
    // XCD-exclusive channel-group ownership: blocks round-robin across XCDs
    // (xcd = bid % 8), so give each XCD a contiguous slice of channel groups.
    // Each map plane is then resident in exactly ONE per-XCD L2 (no 8x dup).
    int bid = blockIdx.x;
    int xcd = bid & 7;
    int j   = bid >> 3;            // per-XCD linear block index (time-ordered)
    int g_local = j / NBX;         // group-major within XCD: sequential planes
    int nb      = j - g_local * NBX;
    int g   = xcd * GPX + g_local;

    int n = nb * 256 + threadIdx.x;
    if (n >= N) return;

    float dsf = (float)dsp[0];
    float2 p = ((const float2*)uv)[n];     // 8B aligned, coalesced
    float u = p.x / dsf;
    float v = p.y / dsf;

    int u_lo = (int)u;                      // trunc == floor (u,v >= 0)
    int v_lo = (int)v;
    float du = u - (float)u_lo;
    float dv = v - (float)v_lo;

    float w00 = (1.0f - dv) * (1.0f - du);
    float w10 = dv * (1.0f - du);
    float w01 = (1.0f - dv) * du;
    float w11 = dv * du;

    int cbase = g * CPG;
    const float* fp = fmap + (size_t)cbase * HW + (size_t)v_lo * W + u_lo;
    float*       op = out  + (size_t)cbase * N + n;

#pragma unroll
    for (int c = 0; c < CPG; ++c) {
        float f00 = fp[0];
        float f01 = fp[1];
        float f10 = fp[W];
        float f11 = fp[W + 1];
        float r = f00 * w00 + f10 * w10 + f01 * w01 + f11 * w11;
        __builtin_nontemporal_store(r, op);   // streaming output: don't pollute L2/L3
        fp += HW;
        op += N;
    }
}

extern "C" void kernel_launch(void* const* d_in, const int* in_sizes, int n_in,
                              void* d_out, int out_size, void* d_ws, size_t ws_size,
                              hipStream_t stream)
{
    const float* fmap = (const float*)d_in[0];
    const float* uv   = (const float*)d_in[1];
    const int*   dsp  = (const int*)d_in[2];
    float*       out  = (float*)d_out;

    int N = in_sizes[1] / 2;            // target_uv has N*2 elements
    int NBX = (N + 255) / 256;          // blocks along the point dimension

    dim3 grid(NBX * CG);                // flattened: (group, nblock) swizzled by XCD
    dim3 block(256);
    BilinearResampling_kernel<<<grid, block, 0, stream>>>(fmap, uv, dsp, out, N, NBX);
}